// Round 1
// baseline (198.709 us; speedup 1.0000x reference)
//
#include <hip/hip_runtime.h>
#include <math.h>

#define D_MODEL 1024
#define SEQ 2048
#define SCALE 0.03125f

using bf16x8 = __attribute__((ext_vector_type(8))) short;
using f32x4  = __attribute__((ext_vector_type(4))) float;

__device__ __forceinline__ unsigned short f2bf(float f) {
  union { float f; unsigned int u; } v; v.f = f;
  return (unsigned short)((v.u + 0x7fffu + ((v.u >> 16) & 1u)) >> 16);
}

__device__ __forceinline__ void async_cp16(const void* g, void* l) {
  __builtin_amdgcn_global_load_lds(
      (const __attribute__((address_space(1))) void*)g,
      (__attribute__((address_space(3))) void*)l, 16, 0, 0);
}

// ============================================================================
// 256x128-tile ring-3 pipelined GEMM core: C[256x128] = A(rows) x B^T(rows),
// K = 1024, BK = 64, 512 threads = 8 waves (wm = w>>1 in 0..3 -> 64 rows,
// wn = w&1 -> 64 cols). LDS ring of 3 slots, each A 256x64 + B 128x64 bf16
// (48 KiB) -> 144 KiB total. While computing tile kt (slot kt%3) we stage
// tile kt+2 into slot (kt+2)%3. Tile entry: s_waitcnt vmcnt(6) + raw
// s_barrier -- next tile's 6 loads stay in flight across the barrier.
// LDS swizzle: 16B chunk c of row r stored at chunk c ^ (r&7); staging
// pre-swizzles the GLOBAL source (global_load_lds writes linearly), frag
// ds_read_b128 applies the same XOR -> 2-way (free) bank aliasing.
// ============================================================================

#define ASLOT 16384  // shorts per A slot (256*64)
#define BSLOT 8192   // shorts per B slot (128*64)

// Stage one K-tile (A 256x64: 4 rounds, B 128x64: 2 rounds) of K-tile index
// kt into ring slot s. sA/sB are per-thread pre-swizzled source pointers.
__device__ __forceinline__ void stage_tile(const unsigned short* sA,
                                           const unsigned short* sB,
                                           unsigned short* As,
                                           unsigned short* Bs, int s, int kt,
                                           int t) {
  const unsigned short* a = sA + kt * 64;
  const unsigned short* b = sB + kt * 64;
  unsigned short* da = As + s * ASLOT + t * 8;
  unsigned short* db = Bs + s * BSLOT + t * 8;
  async_cp16(a, da);
  async_cp16(a + 64 * D_MODEL, da + 4096);
  async_cp16(a + 128 * D_MODEL, da + 8192);
  async_cp16(a + 192 * D_MODEL, da + 12288);
  async_cp16(b, db);
  async_cp16(b + 64 * D_MODEL, db + 4096);
}

template <bool STG>
__device__ __forceinline__ void tile_body(unsigned short* As, unsigned short* Bs,
                                          int slot, int s2, int ktN,
                                          const unsigned short* sA,
                                          const unsigned short* sB, int t,
                                          int aoff, int boff, int ka0, int ka1,
                                          f32x4 (&acc)[4][4]) {
  const unsigned short* Ab = As + slot * ASLOT + aoff;
  const unsigned short* Bb = Bs + slot * BSLOT + boff;
  bf16x8 bfr[4][2], afr[2][2], afr2[2][2];
  // phase 0: all B frags + A frags mt=0,1
  #pragma unroll
  for (int nt = 0; nt < 4; nt++) {
    bfr[nt][0] = *(const bf16x8*)(Bb + nt * 1024 + ka0);
    bfr[nt][1] = *(const bf16x8*)(Bb + nt * 1024 + ka1);
  }
  #pragma unroll
  for (int mt = 0; mt < 2; mt++) {
    afr[mt][0] = *(const bf16x8*)(Ab + mt * 1024 + ka0);
    afr[mt][1] = *(const bf16x8*)(Ab + mt * 1024 + ka1);
  }
  if (STG) stage_tile(sA, sB, As, Bs, s2, ktN, t);
  __builtin_amdgcn_s_setprio(1);
  #pragma unroll
  for (int ks = 0; ks < 2; ks++)
    #pragma unroll
    for (int mt = 0; mt < 2; mt++)
      #pragma unroll
      for (int nt = 0; nt < 4; nt++)
        acc[mt][nt] = __builtin_amdgcn_mfma_f32_16x16x32_bf16(
            afr[mt][ks], bfr[nt][ks], acc[mt][nt], 0, 0, 0);
  __builtin_amdgcn_s_setprio(0);
  // phase 1: A frags mt=2,3
  #pragma unroll
  for (int mt = 0; mt < 2; mt++) {
    afr2[mt][0] = *(const bf16x8*)(Ab + (2 + mt) * 1024 + ka0);
    afr2[mt][1] = *(const bf16x8*)(Ab + (2 + mt) * 1024 + ka1);
  }
  __builtin_amdgcn_s_setprio(1);
  #pragma unroll
  for (int ks = 0; ks < 2; ks++)
    #pragma unroll
    for (int mt = 0; mt < 2; mt++)
      #pragma unroll
      for (int nt = 0; nt < 4; nt++)
        acc[2 + mt][nt] = __builtin_amdgcn_mfma_f32_16x16x32_bf16(
            afr2[mt][ks], bfr[nt][ks], acc[2 + mt][nt], 0, 0, 0);
  __builtin_amdgcn_s_setprio(0);
}

#define PIPE_SYNC(N)                                      \
  asm volatile("s_waitcnt vmcnt(" #N ")" ::: "memory");   \
  __builtin_amdgcn_s_barrier();                           \
  asm volatile("" ::: "memory")

__device__ __forceinline__ void gemm256x128(const unsigned short* gA,
                                            const unsigned short* gB,
                                            unsigned short* As,
                                            unsigned short* Bs, int t,
                                            f32x4 (&acc)[4][4]) {
  // per-thread pre-swizzled staging sources: thread t covers row (t>>3) of a
  // 64-row round, physical chunk t&7 <- logical chunk (t&7)^(row&7)
  const int srow = t >> 3;
  const int schk = (t & 7) ^ (srow & 7);
  const unsigned short* sA = gA + srow * D_MODEL + schk * 8;
  const unsigned short* sB = gB + srow * D_MODEL + schk * 8;
  const int lane = t & 63, w = t >> 6;
  const int wm = w >> 1, wn = w & 1;
  const int l16 = lane & 15, quad = lane >> 4, x7 = l16 & 7;
  const int aoff = (wm * 64 + l16) * 64;
  const int boff = (wn * 64 + l16) * 64;
  const int ka0 = (quad ^ x7) * 8;
  const int ka1 = ((4 | quad) ^ x7) * 8;

  stage_tile(sA, sB, As, Bs, 0, 0, t);
  stage_tile(sA, sB, As, Bs, 1, 1, t);

  int slot = 0, s2 = 2;
  for (int kt = 0; kt < 14; ++kt) {
    PIPE_SYNC(6);  // retire tile kt's 6 loads; tile kt+1's stay in flight
    tile_body<true>(As, Bs, slot, s2, kt + 2, sA, sB, t, aoff, boff, ka0, ka1,
                    acc);
    slot = (slot == 2) ? 0 : slot + 1;
    s2 = (s2 == 2) ? 0 : s2 + 1;
  }
  PIPE_SYNC(6);  // kt = 14 (slot 2), no stage
  tile_body<false>(As, Bs, 2, 0, 0, sA, sB, t, aoff, boff, ka0, ka1, acc);
  PIPE_SYNC(0);  // kt = 15 (slot 0), drain
  tile_body<false>(As, Bs, 0, 0, 0, sA, sB, t, aoff, boff, ka0, ka1, acc);
}

__device__ __forceinline__ void store_bf16_256x128(f32x4 (&acc)[4][4],
                                                   unsigned short* C, int ldc,
                                                   int m0, int n0, int t) {
  const int lane = t & 63, w = t >> 6;
  const int wm = w >> 1, wn = w & 1;
  const int l16 = lane & 15, quad = lane >> 4;
  #pragma unroll
  for (int mt = 0; mt < 4; mt++) {
    #pragma unroll
    for (int r = 0; r < 4; r++) {
      const int row = m0 + wm * 64 + mt * 16 + quad * 4 + r;
      unsigned short* cp = C + (size_t)row * ldc + n0 + wn * 64 + l16;
      #pragma unroll
      for (int nt = 0; nt < 4; nt++) cp[nt * 16] = f2bf(acc[mt][nt][r]);
    }
  }
}

// ---- wcvt: W fp32 -> bf16 rows; u = Wq bk, v = Wk bq, sc = scale*(bq.bk) ----
__global__ __launch_bounds__(256) void wcvt_kernel(
    const float* __restrict__ Wq, const float* __restrict__ Wk,
    const float* __restrict__ bq, const float* __restrict__ bk,
    unsigned short* __restrict__ Wqb, unsigned short* __restrict__ Wkb,
    float* __restrict__ u, float* __restrict__ v, float* __restrict__ sc) {
  const int blk = blockIdx.x, tid = threadIdx.x;
  __shared__ float red[4];
  float p;
  if (blk < 2048) {
    const bool isq = blk < 1024;
    const int row = blk & 1023;
    const float* W = isq ? Wq : Wk;
    const float* bias = isq ? bk : bq;
    const float4 wv = ((const float4*)(W + (size_t)row * D_MODEL))[tid];
    const float4 bv = ((const float4*)bias)[tid];
    ushort4 o;
    o.x = f2bf(wv.x); o.y = f2bf(wv.y); o.z = f2bf(wv.z); o.w = f2bf(wv.w);
    ((ushort4*)((isq ? Wqb : Wkb) + (size_t)row * D_MODEL))[tid] = o;
    p = wv.x * bv.x + wv.y * bv.y + wv.z * bv.z + wv.w * bv.w;
    #pragma unroll
    for (int off = 32; off > 0; off >>= 1) p += __shfl_down(p, off, 64);
    if ((tid & 63) == 0) red[tid >> 6] = p;
    __syncthreads();
    if (tid == 0) (isq ? u : v)[row] = red[0] + red[1] + red[2] + red[3];
  } else {
    const float4 a = ((const float4*)bq)[tid];
    const float4 b = ((const float4*)bk)[tid];
    p = a.x * b.x + a.y * b.y + a.z * b.z + a.w * b.w;
    #pragma unroll
    for (int off = 32; off > 0; off >>= 1) p += __shfl_down(p, off, 64);
    if ((tid & 63) == 0) red[tid >> 6] = p;
    __syncthreads();
    if (tid == 0) sc[0] = SCALE * (red[0] + red[1] + red[2] + red[3]);
  }
}

// ---- prep_x: xb=bf16(x); t=tanh(x.Wo+bo); aa=scale*(x.u)+sc; bb=scale*(x.v) ----
__global__ __launch_bounds__(256) void prep_x_kernel(
    const float* __restrict__ x, const float* __restrict__ Wo,
    const float* __restrict__ bo, const float* __restrict__ u,
    const float* __restrict__ v, const float* __restrict__ sc,
    unsigned short* __restrict__ xb, float* __restrict__ tb,
    float* __restrict__ aa, float* __restrict__ bb) {
  const int m = blockIdx.x, tid = threadIdx.x;
  const float4 xv = ((const float4*)(x + (size_t)m * D_MODEL))[tid];
  const float4 wv = ((const float4*)Wo)[tid];
  const float4 uv = ((const float4*)u)[tid];
  const float4 vv = ((const float4*)v)[tid];
  ushort4 o;
  o.x = f2bf(xv.x); o.y = f2bf(xv.y); o.z = f2bf(xv.z); o.w = f2bf(xv.w);
  ((ushort4*)(xb + (size_t)m * D_MODEL))[tid] = o;
  float p0 = xv.x * wv.x + xv.y * wv.y + xv.z * wv.z + xv.w * wv.w;
  float p1 = xv.x * uv.x + xv.y * uv.y + xv.z * uv.z + xv.w * uv.w;
  float p2 = xv.x * vv.x + xv.y * vv.y + xv.z * vv.z + xv.w * vv.w;
  #pragma unroll
  for (int off = 32; off > 0; off >>= 1) {
    p0 += __shfl_down(p0, off, 64);
    p1 += __shfl_down(p1, off, 64);
    p2 += __shfl_down(p2, off, 64);
  }
  __shared__ float red[3][4];
  if ((tid & 63) == 0) {
    red[0][tid >> 6] = p0; red[1][tid >> 6] = p1; red[2][tid >> 6] = p2;
  }
  __syncthreads();
  if (tid == 0) {
    tb[m] = tanhf(red[0][0] + red[0][1] + red[0][2] + red[0][3] + bo[0]);
    aa[m] = SCALE * (red[1][0] + red[1][1] + red[1][2] + red[1][3]) + sc[0];
    bb[m] = SCALE * (red[2][0] + red[2][1] + red[2][2] + red[2][3]);
  }
}

// ---- wmm: Mt[d2,d1] = sum_e Wk[d2,e]*Wq[d1,e]  (A=Wkb, B^T=Wqb) ----
__global__ __launch_bounds__(512, 2) void wmm_kernel(
    const unsigned short* __restrict__ Wkb,
    const unsigned short* __restrict__ Wqb, unsigned short* __restrict__ Mt) {
  __shared__ unsigned short As[3 * ASLOT], Bs[3 * BSLOT];
  const int n0 = blockIdx.x * 128, m0 = blockIdx.y * 256;
  const int t = threadIdx.x;
  f32x4 acc[4][4];
  #pragma unroll
  for (int i = 0; i < 4; i++)
    #pragma unroll
    for (int j = 0; j < 4; j++) acc[i][j] = f32x4{0.f, 0.f, 0.f, 0.f};
  gemm256x128(Wkb + (size_t)m0 * D_MODEL, Wqb + (size_t)n0 * D_MODEL, As, Bs, t,
              acc);
  store_bf16_256x128(acc, Mt, D_MODEL, m0, n0, t);
}

// ---- zgen: Zb = xb @ M  (B^T = Mt rows) ----
__global__ __launch_bounds__(512, 2) void zgen_kernel(
    const unsigned short* __restrict__ xb,
    const unsigned short* __restrict__ Mt, unsigned short* __restrict__ Zb) {
  __shared__ unsigned short As[3 * ASLOT], Bs[3 * BSLOT];
  const int n0 = blockIdx.x * 128, m0 = blockIdx.y * 256;
  const int t = threadIdx.x;
  f32x4 acc[4][4];
  #pragma unroll
  for (int i = 0; i < 4; i++)
    #pragma unroll
    for (int j = 0; j < 4; j++) acc[i][j] = f32x4{0.f, 0.f, 0.f, 0.f};
  gemm256x128(xb + (size_t)m0 * D_MODEL, Mt + (size_t)n0 * D_MODEL, As, Bs, t,
              acc);
  store_bf16_256x128(acc, Zb, D_MODEL, m0, n0, t);
}

// ---- zxt: out[b,i,j] = scale*(Z_i . x_j) + aa_i + bb_j + 5*tanh(s_j-s_i) ----
__global__ __launch_bounds__(512, 2) void zxt_kernel(
    const unsigned short* __restrict__ Zb, const unsigned short* __restrict__ xb,
    const float* __restrict__ tb, const float* __restrict__ aa,
    const float* __restrict__ bb, float* __restrict__ out) {
  __shared__ unsigned short As[3 * ASLOT], Bs[3 * BSLOT];
  __shared__ float tsi[256], tsa[256], tsj[128], tsb2[128];
  const int b = blockIdx.z;
  const int j0 = blockIdx.x * 128, i0 = blockIdx.y * 256;
  const int t = threadIdx.x;
  f32x4 acc[4][4];
  #pragma unroll
  for (int i = 0; i < 4; i++)
    #pragma unroll
    for (int j = 0; j < 4; j++) acc[i][j] = f32x4{0.f, 0.f, 0.f, 0.f};
  gemm256x128(Zb + ((size_t)b * SEQ + i0) * D_MODEL,
              xb + ((size_t)b * SEQ + j0) * D_MODEL, As, Bs, t, acc);

  // bias vectors loaded AFTER the pipeline so they don't perturb vmcnt counts
  if (t < 256) {
    tsi[t] = tb[b * SEQ + i0 + t];
    tsa[t] = aa[b * SEQ + i0 + t];
  } else if (t < 384) {
    tsj[t - 256] = tb[b * SEQ + j0 + t - 256];
    tsb2[t - 256] = bb[b * SEQ + j0 + t - 256];
  }
  __syncthreads();

  const int lane = t & 63, w = t >> 6;
  const int wm = w >> 1, wn = w & 1;
  const int l16 = lane & 15, quad = lane >> 4;
  float tj[4], bj[4];
  #pragma unroll
  for (int nt = 0; nt < 4; nt++) {
    tj[nt] = tsj[wn * 64 + nt * 16 + l16];
    bj[nt] = tsb2[wn * 64 + nt * 16 + l16];
  }
  #pragma unroll
  for (int mt = 0; mt < 4; mt++) {
    #pragma unroll
    for (int r = 0; r < 4; r++) {
      const int il = wm * 64 + mt * 16 + quad * 4 + r;
      const float ti = tsi[il];
      const float ai = tsa[il];
      float* cp =
          out + ((size_t)(b * SEQ + i0 + il)) * SEQ + j0 + wn * 64 + l16;
      #pragma unroll
      for (int nt = 0; nt < 4; nt++) {
        const float num = tj[nt] - ti;
        const float den = fmaf(-tj[nt], ti, 1.0f);
        const float obias = 5.0f * num * __builtin_amdgcn_rcpf(den);
        cp[nt * 16] = SCALE * acc[mt][nt][r] + ai + bj[nt] + obias;
      }
    }
  }
}

extern "C" void kernel_launch(void* const* d_in, const int* in_sizes, int n_in,
                              void* d_out, int out_size, void* d_ws,
                              size_t ws_size, hipStream_t stream) {
  const float* x  = (const float*)d_in[0];
  const float* Wq = (const float*)d_in[1];
  const float* bq = (const float*)d_in[2];
  const float* Wk = (const float*)d_in[3];
  const float* bk = (const float*)d_in[4];
  const float* Wo = (const float*)d_in[5];
  const float* bo = (const float*)d_in[6];
  float* out = (float*)d_out;

  char* ws = (char*)d_ws;
  unsigned short* xb  = (unsigned short*)(ws);                      // 16 MiB
  unsigned short* Zb  = (unsigned short*)(ws + (16ull << 20));      // 16 MiB
  unsigned short* Wqb = (unsigned short*)(ws + (32ull << 20));      // 2 MiB
  unsigned short* Wkb = (unsigned short*)(ws + (34ull << 20));      // 2 MiB
  unsigned short* Mt  = (unsigned short*)(ws + (36ull << 20));      // 2 MiB
  float* tb = (float*)(ws + (38ull << 20));                         // 32 KiB
  float* aa = (float*)(ws + (38ull << 20) + (32ull << 10));         // 32 KiB
  float* bb = (float*)(ws + (38ull << 20) + (64ull << 10));         // 32 KiB
  float* u  = (float*)(ws + (38ull << 20) + (96ull << 10));         // 4 KiB
  float* v  = (float*)(ws + (38ull << 20) + (100ull << 10));        // 4 KiB
  float* sc = (float*)(ws + (38ull << 20) + (104ull << 10));        // 4 B

  wcvt_kernel<<<2049, 256, 0, stream>>>(Wq, Wk, bq, bk, Wqb, Wkb, u, v, sc);
  prep_x_kernel<<<8192, 256, 0, stream>>>(x, Wo, bo, u, v, sc, xb, tb, aa, bb);
  wmm_kernel<<<dim3(8, 4), 512, 0, stream>>>(Wkb, Wqb, Mt);
  zgen_kernel<<<dim3(8, 32), 512, 0, stream>>>(xb, Mt, Zb);
  zxt_kernel<<<dim3(16, 8, 4), 512, 0, stream>>>(Zb, xb, tb, aa, bb, out);
}

// Round 2
// 197.069 us; speedup vs baseline: 1.0083x; 1.0083x over previous
//
#include <hip/hip_runtime.h>
#include <math.h>

#define D_MODEL 1024
#define SEQ 2048
#define SCALE 0.03125f

using bf16x8 = __attribute__((ext_vector_type(8))) short;
using f32x4  = __attribute__((ext_vector_type(4))) float;

__device__ __forceinline__ unsigned short f2bf(float f) {
  union { float f; unsigned int u; } v; v.f = f;
  return (unsigned short)((v.u + 0x7fffu + ((v.u >> 16) & 1u)) >> 16);
}

__device__ __forceinline__ void async_cp16(const void* g, void* l) {
  __builtin_amdgcn_global_load_lds(
      (const __attribute__((address_space(1))) void*)g,
      (__attribute__((address_space(3))) void*)l, 16, 0, 0);
}

// ============================================================================
// Round-0 proven 128x128 / 256-thread core (for zgen & wmm).
// ============================================================================
__device__ __forceinline__ const unsigned short* stage_ptr(
    const unsigned short* base, int row0, int ld, int tid) {
  const int r0 = tid >> 2;
  const int s0 = ((tid & 3) ^ ((r0 >> 1) & 3)) * 8;
  return base + (size_t)(row0 + r0) * ld + s0;
}

__device__ __forceinline__ void gemm_core(
    const unsigned short* __restrict__ gA, const unsigned short* __restrict__ gB,
    int lda, int ldb, unsigned short* As, unsigned short* Bs, int tid,
    f32x4 acc[4][4]) {
  const int lane = tid & 63, w = tid >> 6;
  const int wm = w >> 1, wn = w & 1;
  const int l16 = lane & 15, quad = lane >> 4;

  async_cp16(gA,            As + tid * 8);
  async_cp16(gA + 64 * lda, As + 2048 + tid * 8);
  async_cp16(gB,            Bs + tid * 8);
  async_cp16(gB + 64 * ldb, Bs + 2048 + tid * 8);
  __syncthreads();

  #pragma unroll 2
  for (int kk = 0; kk < 32; ++kk) {
    const int cur = (kk & 1) * 4096;
    const int nxt = 4096 - cur;
    if (kk < 31) {
      const unsigned short* a = gA + (kk + 1) * 32;
      const unsigned short* b = gB + (kk + 1) * 32;
      async_cp16(a,            As + nxt + tid * 8);
      async_cp16(a + 64 * lda, As + nxt + 2048 + tid * 8);
      async_cp16(b,            Bs + nxt + tid * 8);
      async_cp16(b + 64 * ldb, Bs + nxt + 2048 + tid * 8);
    }
    bf16x8 afr[4], bfr[4];
    #pragma unroll
    for (int mt = 0; mt < 4; mt++) {
      const int R = wm * 64 + mt * 16 + l16;
      afr[mt] = *(const bf16x8*)(As + cur + (R * 4 + (quad ^ ((R >> 1) & 3))) * 8);
    }
    #pragma unroll
    for (int nt = 0; nt < 4; nt++) {
      const int R = wn * 64 + nt * 16 + l16;
      bfr[nt] = *(const bf16x8*)(Bs + cur + (R * 4 + (quad ^ ((R >> 1) & 3))) * 8);
    }
    #pragma unroll
    for (int mt = 0; mt < 4; mt++)
      #pragma unroll
      for (int nt = 0; nt < 4; nt++)
        acc[mt][nt] = __builtin_amdgcn_mfma_f32_16x16x32_bf16(
            afr[mt], bfr[nt], acc[mt][nt], 0, 0, 0);
    __syncthreads();
  }
}

__device__ __forceinline__ void store_c_bf16(f32x4 acc[4][4],
                                             unsigned short* C, int ldc,
                                             int m0, int n0, int tid) {
  const int lane = tid & 63, w = tid >> 6;
  const int wm = w >> 1, wn = w & 1;
  const int l16 = lane & 15, quad = lane >> 4;
  #pragma unroll
  for (int mt = 0; mt < 4; mt++) {
    #pragma unroll
    for (int r = 0; r < 4; r++) {
      const int row = m0 + wm * 64 + mt * 16 + quad * 4 + r;
      unsigned short* cp = C + (size_t)row * ldc + n0 + wn * 64 + l16;
      #pragma unroll
      for (int nt = 0; nt < 4; nt++) cp[nt * 16] = f2bf(acc[mt][nt][r]);
    }
  }
}

// ---- wcvt: W fp32 -> bf16 rows; u = Wq bk, v = Wk bq, sc = scale*(bq.bk) ----
__global__ __launch_bounds__(256) void wcvt_kernel(
    const float* __restrict__ Wq, const float* __restrict__ Wk,
    const float* __restrict__ bq, const float* __restrict__ bk,
    unsigned short* __restrict__ Wqb, unsigned short* __restrict__ Wkb,
    float* __restrict__ u, float* __restrict__ v, float* __restrict__ sc) {
  const int blk = blockIdx.x, tid = threadIdx.x;
  __shared__ float red[4];
  float p;
  if (blk < 2048) {
    const bool isq = blk < 1024;
    const int row = blk & 1023;
    const float* W = isq ? Wq : Wk;
    const float* bias = isq ? bk : bq;
    const float4 wv = ((const float4*)(W + (size_t)row * D_MODEL))[tid];
    const float4 bv = ((const float4*)bias)[tid];
    ushort4 o;
    o.x = f2bf(wv.x); o.y = f2bf(wv.y); o.z = f2bf(wv.z); o.w = f2bf(wv.w);
    ((ushort4*)((isq ? Wqb : Wkb) + (size_t)row * D_MODEL))[tid] = o;
    p = wv.x * bv.x + wv.y * bv.y + wv.z * bv.z + wv.w * bv.w;
    #pragma unroll
    for (int off = 32; off > 0; off >>= 1) p += __shfl_down(p, off, 64);
    if ((tid & 63) == 0) red[tid >> 6] = p;
    __syncthreads();
    if (tid == 0) (isq ? u : v)[row] = red[0] + red[1] + red[2] + red[3];
  } else {
    const float4 a = ((const float4*)bq)[tid];
    const float4 b = ((const float4*)bk)[tid];
    p = a.x * b.x + a.y * b.y + a.z * b.z + a.w * b.w;
    #pragma unroll
    for (int off = 32; off > 0; off >>= 1) p += __shfl_down(p, off, 64);
    if ((tid & 63) == 0) red[tid >> 6] = p;
    __syncthreads();
    if (tid == 0) sc[0] = SCALE * (red[0] + red[1] + red[2] + red[3]);
  }
}

// ---- prep_x: xb=bf16(x); t=tanh(x.Wo+bo); aa=scale*(x.u)+sc; bb=scale*(x.v) ----
__global__ __launch_bounds__(256) void prep_x_kernel(
    const float* __restrict__ x, const float* __restrict__ Wo,
    const float* __restrict__ bo, const float* __restrict__ u,
    const float* __restrict__ v, const float* __restrict__ sc,
    unsigned short* __restrict__ xb, float* __restrict__ tb,
    float* __restrict__ aa, float* __restrict__ bb) {
  const int m = blockIdx.x, tid = threadIdx.x;
  const float4 xv = ((const float4*)(x + (size_t)m * D_MODEL))[tid];
  const float4 wv = ((const float4*)Wo)[tid];
  const float4 uv = ((const float4*)u)[tid];
  const float4 vv = ((const float4*)v)[tid];
  ushort4 o;
  o.x = f2bf(xv.x); o.y = f2bf(xv.y); o.z = f2bf(xv.z); o.w = f2bf(xv.w);
  ((ushort4*)(xb + (size_t)m * D_MODEL))[tid] = o;
  float p0 = xv.x * wv.x + xv.y * wv.y + xv.z * wv.z + xv.w * wv.w;
  float p1 = xv.x * uv.x + xv.y * uv.y + xv.z * uv.z + xv.w * uv.w;
  float p2 = xv.x * vv.x + xv.y * vv.y + xv.z * vv.z + xv.w * vv.w;
  #pragma unroll
  for (int off = 32; off > 0; off >>= 1) {
    p0 += __shfl_down(p0, off, 64);
    p1 += __shfl_down(p1, off, 64);
    p2 += __shfl_down(p2, off, 64);
  }
  __shared__ float red[3][4];
  if ((tid & 63) == 0) {
    red[0][tid >> 6] = p0; red[1][tid >> 6] = p1; red[2][tid >> 6] = p2;
  }
  __syncthreads();
  if (tid == 0) {
    tb[m] = tanhf(red[0][0] + red[0][1] + red[0][2] + red[0][3] + bo[0]);
    aa[m] = SCALE * (red[1][0] + red[1][1] + red[1][2] + red[1][3]) + sc[0];
    bb[m] = SCALE * (red[2][0] + red[2][1] + red[2][2] + red[2][3]);
  }
}

// ---- wmm: Mt[d2,d1] = sum_e Wk[d2,e]*Wq[d1,e]  (A=Wkb, B^T=Wqb) ----
__global__ __launch_bounds__(256, 3) void wmm_kernel(
    const unsigned short* __restrict__ Wkb,
    const unsigned short* __restrict__ Wqb, unsigned short* __restrict__ Mt) {
  const int m0 = blockIdx.x * 128, n0 = blockIdx.y * 128;
  __shared__ unsigned short As[2 * 4096], Bs[2 * 4096];
  const int tid = threadIdx.x;
  f32x4 acc[4][4];
  #pragma unroll
  for (int i = 0; i < 4; i++)
    #pragma unroll
    for (int j = 0; j < 4; j++) acc[i][j] = f32x4{0.f, 0.f, 0.f, 0.f};
  gemm_core(stage_ptr(Wkb, m0, D_MODEL, tid), stage_ptr(Wqb, n0, D_MODEL, tid),
            D_MODEL, D_MODEL, As, Bs, tid, acc);
  store_c_bf16(acc, Mt, D_MODEL, m0, n0, tid);
}

// ---- zgen: Zb = xb @ M  (B^T = Mt rows) ----
__global__ __launch_bounds__(256, 3) void zgen_kernel(
    const unsigned short* __restrict__ xb,
    const unsigned short* __restrict__ Mt, unsigned short* __restrict__ Zb) {
  const int m0 = blockIdx.x * 128, n0 = blockIdx.y * 128;
  __shared__ unsigned short As[2 * 4096], Bs[2 * 4096];
  const int tid = threadIdx.x;
  f32x4 acc[4][4];
  #pragma unroll
  for (int i = 0; i < 4; i++)
    #pragma unroll
    for (int j = 0; j < 4; j++) acc[i][j] = f32x4{0.f, 0.f, 0.f, 0.f};
  gemm_core(stage_ptr(xb, m0, D_MODEL, tid), stage_ptr(Mt, n0, D_MODEL, tid),
            D_MODEL, D_MODEL, As, Bs, tid, acc);
  store_c_bf16(acc, Zb, D_MODEL, m0, n0, tid);
}

// ============================================================================
// zxt: m201-style 8-phase 256x256 template. 512 threads = 8 waves (2M x 4N),
// per-wave C = 128x64. BK=64, double-buffered; each buffer holds A/B as two
// 128-row halves of 64 K-elems. LDS swizzle: 16B chunk c of row r at phys
// chunk c^(r&7) (2-way bank alias = free; verified 0 conflicts).
// Phase: {ds_read frags; stage 1 half-tile (2 global_load_lds);
//         vmcnt(6) @ph4/ph8; s_barrier; lgkmcnt(0); setprio1; 16 MFMA;
//         setprio0; s_barrier}.
// Stage schedule (iter i computes ktiles 2i[buf0: ph1-4], 2i+1[buf1: ph5-8]):
//   ph1: Ah1(2i+1)->buf1  ph2: Bh0(2i+2)->buf0  ph3: Bh1(2i+2)
//   ph4: Ah0(2i+2)        ph5: Ah1(2i+2)        ph6: Bh0(2i+3)->buf1
//   ph7: Bh1(2i+3)        ph8: Ah0(2i+3)
// Each half is overwritten only after its last read (B: 1 phase after; A at
// ph4/ph8 after that phase's ds_reads -- template-standard). vmcnt(6) = 3
// half-tiles in flight. Prologue stages 7 halves, epilogue iter drains.
// ============================================================================

#define STAGE2(S, D) { async_cp16((S), (D)); \
                       async_cp16((S) + 64 * D_MODEL, (D) + 4096); }

#define PHASE(Q, AB, BB, LOADB, STG, VM) {                                   \
    bf16x8 afr[2][2];                                                        \
    if (LOADB) {                                                             \
      _Pragma("unroll") for (int nt = 0; nt < 4; nt++) {                     \
        bfr[nt][0] = *(const bf16x8*)((BB) + brow + nt * 1024 + c0);         \
        bfr[nt][1] = *(const bf16x8*)((BB) + brow + nt * 1024 + c1);         \
      }                                                                      \
    }                                                                        \
    _Pragma("unroll") for (int mt = 0; mt < 2; mt++) {                       \
      afr[mt][0] = *(const bf16x8*)((AB) + arow + (Q)*2048 + mt*1024 + c0);  \
      afr[mt][1] = *(const bf16x8*)((AB) + arow + (Q)*2048 + mt*1024 + c1);  \
    }                                                                        \
    STG;                                                                     \
    if ((VM) == 6) asm volatile("s_waitcnt vmcnt(6)" ::: "memory");          \
    if ((VM) == 0) asm volatile("s_waitcnt vmcnt(0)" ::: "memory");          \
    __builtin_amdgcn_s_barrier();                                            \
    asm volatile("s_waitcnt lgkmcnt(0)" ::: "memory");                       \
    __builtin_amdgcn_s_setprio(1);                                           \
    _Pragma("unroll") for (int ks = 0; ks < 2; ks++)                         \
      _Pragma("unroll") for (int mt = 0; mt < 2; mt++)                       \
        _Pragma("unroll") for (int nt = 0; nt < 4; nt++)                     \
          acc[(Q)*2 + mt][nt] = __builtin_amdgcn_mfma_f32_16x16x32_bf16(     \
              afr[mt][ks], bfr[nt][ks], acc[(Q)*2 + mt][nt], 0, 0, 0);       \
    __builtin_amdgcn_s_setprio(0);                                           \
    __builtin_amdgcn_s_barrier();                                            \
  }

#define NOSTAGE ((void)0)

__global__ __launch_bounds__(512, 2) void zxt_kernel(
    const unsigned short* __restrict__ Zb, const unsigned short* __restrict__ xb,
    const float* __restrict__ tb, const float* __restrict__ aa,
    const float* __restrict__ bb, float* __restrict__ out) {
  __shared__ unsigned short As[32768], Bs[32768];  // [2 buf][2 half][128*64]
  __shared__ float tsi[256], tsa[256], tsj[256], tsb2[256];
  const int b = blockIdx.z;
  const int j0 = blockIdx.x * 256, i0 = blockIdx.y * 256;
  const int t = threadIdx.x;
  const int lane = t & 63, w = t >> 6;
  const int wm = w >> 2, wn = w & 3;
  const int l16 = lane & 15, quad = lane >> 4, x7 = l16 & 7;
  const int c0 = (quad ^ x7) * 8, c1 = ((4 | quad) ^ x7) * 8;
  const int arow = l16 * 64;
  const int brow = ((wn & 1) * 64 + l16) * 64;

  // per-wave LDS fragment bases
  const unsigned short* A0 = As + wm * 8192;
  const unsigned short* A1 = As + 16384 + wm * 8192;
  const unsigned short* B0 = Bs + (wn >> 1) * 8192;
  const unsigned short* B1 = Bs + 16384 + (wn >> 1) * 8192;

  // staging: thread t covers rows r0, r0+64 of a 128-row half, pre-swizzled
  const int r0 = t >> 3;
  const int sc_ = (t & 7) ^ (r0 & 7);
  const unsigned short* sA =
      Zb + ((size_t)b * SEQ + i0 + r0) * D_MODEL + sc_ * 8;
  const unsigned short* sB =
      xb + ((size_t)b * SEQ + j0 + r0) * D_MODEL + sc_ * 8;
  unsigned short* dA = As + t * 8;
  unsigned short* dB = Bs + t * 8;

  f32x4 acc[8][4];
  #pragma unroll
  for (int i = 0; i < 8; i++)
    #pragma unroll
    for (int j = 0; j < 4; j++) acc[i][j] = f32x4{0.f, 0.f, 0.f, 0.f};
  bf16x8 bfr[4][2];

  // prologue: ktile0 {Bh0,Bh1,Ah0,Ah1} -> buf0; ktile1 {Bh0,Bh1,Ah0} -> buf1
  STAGE2(sB,                       dB);
  STAGE2(sB + 128 * D_MODEL,       dB + 8192);
  STAGE2(sA,                       dA);
  STAGE2(sA + 128 * D_MODEL,       dA + 8192);
  STAGE2(sB + 64,                  dB + 16384);
  STAGE2(sB + 128 * D_MODEL + 64,  dB + 16384 + 8192);
  STAGE2(sA + 64,                  dA + 16384);
  asm volatile("s_waitcnt vmcnt(6)" ::: "memory");
  __builtin_amdgcn_s_barrier();

  for (int i = 0; i < 7; ++i) {
    const int k1o = (2 * i + 1) * 64;
    const int k2o = (2 * i + 2) * 64;
    const int k3o = (2 * i + 3) * 64;
    PHASE(0, A0, B0, 1, STAGE2(sA + 128 * D_MODEL + k1o, dA + 16384 + 8192), -1);
    PHASE(1, A0, B0, 0, STAGE2(sB + k2o, dB), -1);
    PHASE(2, A0, B0, 0, STAGE2(sB + 128 * D_MODEL + k2o, dB + 8192), -1);
    PHASE(3, A0, B0, 0, STAGE2(sA + k2o, dA), 6);
    PHASE(0, A1, B1, 1, STAGE2(sA + 128 * D_MODEL + k2o, dA + 8192), -1);
    PHASE(1, A1, B1, 0, STAGE2(sB + k3o, dB + 16384), -1);
    PHASE(2, A1, B1, 0, STAGE2(sB + 128 * D_MODEL + k3o, dB + 16384 + 8192), -1);
    PHASE(3, A1, B1, 0, STAGE2(sA + k3o, dA + 16384), 6);
  }
  // epilogue iteration: ktiles 14 (buf0) and 15 (buf1)
  PHASE(0, A0, B0, 1, STAGE2(sA + 128 * D_MODEL + 15 * 64, dA + 16384 + 8192), -1);
  PHASE(1, A0, B0, 0, NOSTAGE, -1);
  PHASE(2, A0, B0, 0, NOSTAGE, -1);
  PHASE(3, A0, B0, 0, NOSTAGE, 0);
  PHASE(0, A1, B1, 1, NOSTAGE, -1);
  PHASE(1, A1, B1, 0, NOSTAGE, -1);
  PHASE(2, A1, B1, 0, NOSTAGE, -1);
  PHASE(3, A1, B1, 0, NOSTAGE, -1);

  // bias vectors (after pipeline so vmcnt counts stay clean)
  if (t < 256) {
    tsi[t] = tb[b * SEQ + i0 + t];
    tsa[t] = aa[b * SEQ + i0 + t];
  } else {
    tsj[t - 256] = tb[b * SEQ + j0 + t - 256];
    tsb2[t - 256] = bb[b * SEQ + j0 + t - 256];
  }
  __syncthreads();

  float tj[4], bj[4];
  #pragma unroll
  for (int nt = 0; nt < 4; nt++) {
    tj[nt] = tsj[wn * 64 + nt * 16 + l16];
    bj[nt] = tsb2[wn * 64 + nt * 16 + l16];
  }
  #pragma unroll
  for (int m8 = 0; m8 < 8; m8++) {
    #pragma unroll
    for (int r = 0; r < 4; r++) {
      const int il = wm * 128 + (m8 >> 1) * 32 + (m8 & 1) * 16 + quad * 4 + r;
      const float ti = tsi[il];
      const float ai = tsa[il];
      float* cp =
          out + ((size_t)(b * SEQ + i0 + il)) * SEQ + j0 + wn * 64 + l16;
      #pragma unroll
      for (int nt = 0; nt < 4; nt++) {
        const float num = tj[nt] - ti;
        const float den = fmaf(-tj[nt], ti, 1.0f);
        const float obias = 5.0f * num * __builtin_amdgcn_rcpf(den);
        cp[nt * 16] = SCALE * acc[m8][nt][r] + ai + bj[nt] + obias;
      }
    }
  }
}

extern "C" void kernel_launch(void* const* d_in, const int* in_sizes, int n_in,
                              void* d_out, int out_size, void* d_ws,
                              size_t ws_size, hipStream_t stream) {
  const float* x  = (const float*)d_in[0];
  const float* Wq = (const float*)d_in[1];
  const float* bq = (const float*)d_in[2];
  const float* Wk = (const float*)d_in[3];
  const float* bk = (const float*)d_in[4];
  const float* Wo = (const float*)d_in[5];
  const float* bo = (const float*)d_in[6];
  float* out = (float*)d_out;

  char* ws = (char*)d_ws;
  unsigned short* xb  = (unsigned short*)(ws);                      // 16 MiB
  unsigned short* Zb  = (unsigned short*)(ws + (16ull << 20));      // 16 MiB
  unsigned short* Wqb = (unsigned short*)(ws + (32ull << 20));      // 2 MiB
  unsigned short* Wkb = (unsigned short*)(ws + (34ull << 20));      // 2 MiB
  unsigned short* Mt  = (unsigned short*)(ws + (36ull << 20));      // 2 MiB
  float* tb = (float*)(ws + (38ull << 20));                         // 32 KiB
  float* aa = (float*)(ws + (38ull << 20) + (32ull << 10));         // 32 KiB
  float* bb = (float*)(ws + (38ull << 20) + (64ull << 10));         // 32 KiB
  float* u  = (float*)(ws + (38ull << 20) + (96ull << 10));         // 4 KiB
  float* v  = (float*)(ws + (38ull << 20) + (100ull << 10));        // 4 KiB
  float* sc = (float*)(ws + (38ull << 20) + (104ull << 10));        // 4 B

  wcvt_kernel<<<2049, 256, 0, stream>>>(Wq, Wk, bq, bk, Wqb, Wkb, u, v, sc);
  prep_x_kernel<<<8192, 256, 0, stream>>>(x, Wo, bo, u, v, sc, xb, tb, aa, bb);
  wmm_kernel<<<dim3(8, 8), 256, 0, stream>>>(Wkb, Wqb, Mt);
  zgen_kernel<<<dim3(64, 8), 256, 0, stream>>>(xb, Mt, Zb);
  zxt_kernel<<<dim3(8, 8, 4), 512, 0, stream>>>(Zb, xb, tb, aa, bb, out);
}

// Round 3
// 194.096 us; speedup vs baseline: 1.0238x; 1.0153x over previous
//
#include <hip/hip_runtime.h>
#include <math.h>

#define D_MODEL 1024
#define SEQ 2048
#define SCALE 0.03125f

using bf16x8 = __attribute__((ext_vector_type(8))) short;
using f32x4  = __attribute__((ext_vector_type(4))) float;

__device__ __forceinline__ unsigned short f2bf(float f) {
  union { float f; unsigned int u; } v; v.f = f;
  return (unsigned short)((v.u + 0x7fffu + ((v.u >> 16) & 1u)) >> 16);
}

__device__ __forceinline__ void async_cp16(const void* g, void* l) {
  __builtin_amdgcn_global_load_lds(
      (const __attribute__((address_space(1))) void*)g,
      (__attribute__((address_space(3))) void*)l, 16, 0, 0);
}

// ============================================================================
// Round-0 proven 128x128 / 256-thread core (for zgen & wmm).
// ============================================================================
__device__ __forceinline__ const unsigned short* stage_ptr(
    const unsigned short* base, int row0, int ld, int tid) {
  const int r0 = tid >> 2;
  const int s0 = ((tid & 3) ^ ((r0 >> 1) & 3)) * 8;
  return base + (size_t)(row0 + r0) * ld + s0;
}

__device__ __forceinline__ void gemm_core(
    const unsigned short* __restrict__ gA, const unsigned short* __restrict__ gB,
    int lda, int ldb, unsigned short* As, unsigned short* Bs, int tid,
    f32x4 acc[4][4]) {
  const int lane = tid & 63, w = tid >> 6;
  const int wm = w >> 1, wn = w & 1;
  const int l16 = lane & 15, quad = lane >> 4;

  async_cp16(gA,            As + tid * 8);
  async_cp16(gA + 64 * lda, As + 2048 + tid * 8);
  async_cp16(gB,            Bs + tid * 8);
  async_cp16(gB + 64 * ldb, Bs + 2048 + tid * 8);
  __syncthreads();

  #pragma unroll 2
  for (int kk = 0; kk < 32; ++kk) {
    const int cur = (kk & 1) * 4096;
    const int nxt = 4096 - cur;
    if (kk < 31) {
      const unsigned short* a = gA + (kk + 1) * 32;
      const unsigned short* b = gB + (kk + 1) * 32;
      async_cp16(a,            As + nxt + tid * 8);
      async_cp16(a + 64 * lda, As + nxt + 2048 + tid * 8);
      async_cp16(b,            Bs + nxt + tid * 8);
      async_cp16(b + 64 * ldb, Bs + nxt + 2048 + tid * 8);
    }
    bf16x8 afr[4], bfr[4];
    #pragma unroll
    for (int mt = 0; mt < 4; mt++) {
      const int R = wm * 64 + mt * 16 + l16;
      afr[mt] = *(const bf16x8*)(As + cur + (R * 4 + (quad ^ ((R >> 1) & 3))) * 8);
    }
    #pragma unroll
    for (int nt = 0; nt < 4; nt++) {
      const int R = wn * 64 + nt * 16 + l16;
      bfr[nt] = *(const bf16x8*)(Bs + cur + (R * 4 + (quad ^ ((R >> 1) & 3))) * 8);
    }
    #pragma unroll
    for (int mt = 0; mt < 4; mt++)
      #pragma unroll
      for (int nt = 0; nt < 4; nt++)
        acc[mt][nt] = __builtin_amdgcn_mfma_f32_16x16x32_bf16(
            afr[mt], bfr[nt], acc[mt][nt], 0, 0, 0);
    __syncthreads();
  }
}

__device__ __forceinline__ void store_c_bf16(f32x4 acc[4][4],
                                             unsigned short* C, int ldc,
                                             int m0, int n0, int tid) {
  const int lane = tid & 63, w = tid >> 6;
  const int wm = w >> 1, wn = w & 1;
  const int l16 = lane & 15, quad = lane >> 4;
  #pragma unroll
  for (int mt = 0; mt < 4; mt++) {
    #pragma unroll
    for (int r = 0; r < 4; r++) {
      const int row = m0 + wm * 64 + mt * 16 + quad * 4 + r;
      unsigned short* cp = C + (size_t)row * ldc + n0 + wn * 64 + l16;
      #pragma unroll
      for (int nt = 0; nt < 4; nt++) cp[nt * 16] = f2bf(acc[mt][nt][r]);
    }
  }
}

// ---- wcvt: W fp32 -> bf16 rows; u = Wq bk, v = Wk bq, sc = scale*(bq.bk) ----
__global__ __launch_bounds__(256) void wcvt_kernel(
    const float* __restrict__ Wq, const float* __restrict__ Wk,
    const float* __restrict__ bq, const float* __restrict__ bk,
    unsigned short* __restrict__ Wqb, unsigned short* __restrict__ Wkb,
    float* __restrict__ u, float* __restrict__ v, float* __restrict__ sc) {
  const int blk = blockIdx.x, tid = threadIdx.x;
  __shared__ float red[4];
  float p;
  if (blk < 2048) {
    const bool isq = blk < 1024;
    const int row = blk & 1023;
    const float* W = isq ? Wq : Wk;
    const float* bias = isq ? bk : bq;
    const float4 wv = ((const float4*)(W + (size_t)row * D_MODEL))[tid];
    const float4 bv = ((const float4*)bias)[tid];
    ushort4 o;
    o.x = f2bf(wv.x); o.y = f2bf(wv.y); o.z = f2bf(wv.z); o.w = f2bf(wv.w);
    ((ushort4*)((isq ? Wqb : Wkb) + (size_t)row * D_MODEL))[tid] = o;
    p = wv.x * bv.x + wv.y * bv.y + wv.z * bv.z + wv.w * bv.w;
    #pragma unroll
    for (int off = 32; off > 0; off >>= 1) p += __shfl_down(p, off, 64);
    if ((tid & 63) == 0) red[tid >> 6] = p;
    __syncthreads();
    if (tid == 0) (isq ? u : v)[row] = red[0] + red[1] + red[2] + red[3];
  } else {
    const float4 a = ((const float4*)bq)[tid];
    const float4 b = ((const float4*)bk)[tid];
    p = a.x * b.x + a.y * b.y + a.z * b.z + a.w * b.w;
    #pragma unroll
    for (int off = 32; off > 0; off >>= 1) p += __shfl_down(p, off, 64);
    if ((tid & 63) == 0) red[tid >> 6] = p;
    __syncthreads();
    if (tid == 0) sc[0] = SCALE * (red[0] + red[1] + red[2] + red[3]);
  }
}

// ---- prep_x: xb=bf16(x); t=tanh(x.Wo+bo); aa=scale*(x.u)+sc; bb=scale*(x.v) ----
__global__ __launch_bounds__(256) void prep_x_kernel(
    const float* __restrict__ x, const float* __restrict__ Wo,
    const float* __restrict__ bo, const float* __restrict__ u,
    const float* __restrict__ v, const float* __restrict__ sc,
    unsigned short* __restrict__ xb, float* __restrict__ tb,
    float* __restrict__ aa, float* __restrict__ bb) {
  const int m = blockIdx.x, tid = threadIdx.x;
  const float4 xv = ((const float4*)(x + (size_t)m * D_MODEL))[tid];
  const float4 wv = ((const float4*)Wo)[tid];
  const float4 uv = ((const float4*)u)[tid];
  const float4 vv = ((const float4*)v)[tid];
  ushort4 o;
  o.x = f2bf(xv.x); o.y = f2bf(xv.y); o.z = f2bf(xv.z); o.w = f2bf(xv.w);
  ((ushort4*)(xb + (size_t)m * D_MODEL))[tid] = o;
  float p0 = xv.x * wv.x + xv.y * wv.y + xv.z * wv.z + xv.w * wv.w;
  float p1 = xv.x * uv.x + xv.y * uv.y + xv.z * uv.z + xv.w * uv.w;
  float p2 = xv.x * vv.x + xv.y * vv.y + xv.z * vv.z + xv.w * vv.w;
  #pragma unroll
  for (int off = 32; off > 0; off >>= 1) {
    p0 += __shfl_down(p0, off, 64);
    p1 += __shfl_down(p1, off, 64);
    p2 += __shfl_down(p2, off, 64);
  }
  __shared__ float red[3][4];
  if ((tid & 63) == 0) {
    red[0][tid >> 6] = p0; red[1][tid >> 6] = p1; red[2][tid >> 6] = p2;
  }
  __syncthreads();
  if (tid == 0) {
    tb[m] = tanhf(red[0][0] + red[0][1] + red[0][2] + red[0][3] + bo[0]);
    aa[m] = SCALE * (red[1][0] + red[1][1] + red[1][2] + red[1][3]) + sc[0];
    bb[m] = SCALE * (red[2][0] + red[2][1] + red[2][2] + red[2][3]);
  }
}

// ---- wmm: Mt[d2,d1] = sum_e Wk[d2,e]*Wq[d1,e]  (A=Wkb, B^T=Wqb) ----
__global__ __launch_bounds__(256, 3) void wmm_kernel(
    const unsigned short* __restrict__ Wkb,
    const unsigned short* __restrict__ Wqb, unsigned short* __restrict__ Mt) {
  const int m0 = blockIdx.x * 128, n0 = blockIdx.y * 128;
  __shared__ unsigned short As[2 * 4096], Bs[2 * 4096];
  const int tid = threadIdx.x;
  f32x4 acc[4][4];
  #pragma unroll
  for (int i = 0; i < 4; i++)
    #pragma unroll
    for (int j = 0; j < 4; j++) acc[i][j] = f32x4{0.f, 0.f, 0.f, 0.f};
  gemm_core(stage_ptr(Wkb, m0, D_MODEL, tid), stage_ptr(Wqb, n0, D_MODEL, tid),
            D_MODEL, D_MODEL, As, Bs, tid, acc);
  store_c_bf16(acc, Mt, D_MODEL, m0, n0, tid);
}

// ---- zgen: Zb = xb @ M  (B^T = Mt rows) ----
__global__ __launch_bounds__(256, 3) void zgen_kernel(
    const unsigned short* __restrict__ xb,
    const unsigned short* __restrict__ Mt, unsigned short* __restrict__ Zb) {
  const int m0 = blockIdx.x * 128, n0 = blockIdx.y * 128;
  __shared__ unsigned short As[2 * 4096], Bs[2 * 4096];
  const int tid = threadIdx.x;
  f32x4 acc[4][4];
  #pragma unroll
  for (int i = 0; i < 4; i++)
    #pragma unroll
    for (int j = 0; j < 4; j++) acc[i][j] = f32x4{0.f, 0.f, 0.f, 0.f};
  gemm_core(stage_ptr(xb, m0, D_MODEL, tid), stage_ptr(Mt, n0, D_MODEL, tid),
            D_MODEL, D_MODEL, As, Bs, tid, acc);
  store_c_bf16(acc, Zb, D_MODEL, m0, n0, tid);
}

// ============================================================================
// zxt: m201-style 8-phase 256x256 template (unchanged from round 2) PLUS
// T1 XCD-aware tile mapping. 256 blocks = 32/XCD (hardware assigns
// consecutive dispatch indices round-robin across the 8 XCDs). Each XCD gets
// a 2(i) x 4(j) rectangle of 256^2 tiles per batch: L2 working set =
// 2 A-panels + 4 B-panels = 3 MiB <= 4 MiB per-XCD L2, so panel re-reads
// become L2 hits instead of cross-XCD L3/HBM re-fetches.
// Mapping (bijective): n = z*64+y*8+x; xcd=n&7; q=n>>3; b=q>>3; r=q&7;
//   i_tile = (xcd>>1)*2 + (r>>2); j_tile = (xcd&1)*4 + (r&3).
// ============================================================================

#define STAGE2(S, D) { async_cp16((S), (D)); \
                       async_cp16((S) + 64 * D_MODEL, (D) + 4096); }

#define PHASE(Q, AB, BB, LOADB, STG, VM) {                                   \
    bf16x8 afr[2][2];                                                        \
    if (LOADB) {                                                             \
      _Pragma("unroll") for (int nt = 0; nt < 4; nt++) {                     \
        bfr[nt][0] = *(const bf16x8*)((BB) + brow + nt * 1024 + c0);         \
        bfr[nt][1] = *(const bf16x8*)((BB) + brow + nt * 1024 + c1);         \
      }                                                                      \
    }                                                                        \
    _Pragma("unroll") for (int mt = 0; mt < 2; mt++) {                       \
      afr[mt][0] = *(const bf16x8*)((AB) + arow + (Q)*2048 + mt*1024 + c0);  \
      afr[mt][1] = *(const bf16x8*)((AB) + arow + (Q)*2048 + mt*1024 + c1);  \
    }                                                                        \
    STG;                                                                     \
    if ((VM) == 6) asm volatile("s_waitcnt vmcnt(6)" ::: "memory");          \
    if ((VM) == 0) asm volatile("s_waitcnt vmcnt(0)" ::: "memory");          \
    __builtin_amdgcn_s_barrier();                                            \
    asm volatile("s_waitcnt lgkmcnt(0)" ::: "memory");                       \
    __builtin_amdgcn_s_setprio(1);                                           \
    _Pragma("unroll") for (int ks = 0; ks < 2; ks++)                         \
      _Pragma("unroll") for (int mt = 0; mt < 2; mt++)                       \
        _Pragma("unroll") for (int nt = 0; nt < 4; nt++)                     \
          acc[(Q)*2 + mt][nt] = __builtin_amdgcn_mfma_f32_16x16x32_bf16(     \
              afr[mt][ks], bfr[nt][ks], acc[(Q)*2 + mt][nt], 0, 0, 0);       \
    __builtin_amdgcn_s_setprio(0);                                           \
    __builtin_amdgcn_s_barrier();                                            \
  }

#define NOSTAGE ((void)0)

__global__ __launch_bounds__(512, 2) void zxt_kernel(
    const unsigned short* __restrict__ Zb, const unsigned short* __restrict__ xb,
    const float* __restrict__ tb, const float* __restrict__ aa,
    const float* __restrict__ bb, float* __restrict__ out) {
  __shared__ unsigned short As[32768], Bs[32768];  // [2 buf][2 half][128*64]
  __shared__ float tsi[256], tsa[256], tsj[256], tsb2[256];
  // T1 XCD-aware tile mapping (see header comment)
  const int n = blockIdx.z * 64 + blockIdx.y * 8 + blockIdx.x;
  const int xcd = n & 7, q = n >> 3;
  const int b = q >> 3, r = q & 7;
  const int i0 = ((xcd >> 1) * 2 + (r >> 2)) * 256;
  const int j0 = ((xcd & 1) * 4 + (r & 3)) * 256;
  const int t = threadIdx.x;
  const int lane = t & 63, w = t >> 6;
  const int wm = w >> 2, wn = w & 3;
  const int l16 = lane & 15, quad = lane >> 4, x7 = l16 & 7;
  const int c0 = (quad ^ x7) * 8, c1 = ((4 | quad) ^ x7) * 8;
  const int arow = l16 * 64;
  const int brow = ((wn & 1) * 64 + l16) * 64;

  // per-wave LDS fragment bases
  const unsigned short* A0 = As + wm * 8192;
  const unsigned short* A1 = As + 16384 + wm * 8192;
  const unsigned short* B0 = Bs + (wn >> 1) * 8192;
  const unsigned short* B1 = Bs + 16384 + (wn >> 1) * 8192;

  // staging: thread t covers rows r0, r0+64 of a 128-row half, pre-swizzled
  const int r0 = t >> 3;
  const int sc_ = (t & 7) ^ (r0 & 7);
  const unsigned short* sA =
      Zb + ((size_t)b * SEQ + i0 + r0) * D_MODEL + sc_ * 8;
  const unsigned short* sB =
      xb + ((size_t)b * SEQ + j0 + r0) * D_MODEL + sc_ * 8;
  unsigned short* dA = As + t * 8;
  unsigned short* dB = Bs + t * 8;

  f32x4 acc[8][4];
  #pragma unroll
  for (int i = 0; i < 8; i++)
    #pragma unroll
    for (int j = 0; j < 4; j++) acc[i][j] = f32x4{0.f, 0.f, 0.f, 0.f};
  bf16x8 bfr[4][2];

  // prologue: ktile0 {Bh0,Bh1,Ah0,Ah1} -> buf0; ktile1 {Bh0,Bh1,Ah0} -> buf1
  STAGE2(sB,                       dB);
  STAGE2(sB + 128 * D_MODEL,       dB + 8192);
  STAGE2(sA,                       dA);
  STAGE2(sA + 128 * D_MODEL,       dA + 8192);
  STAGE2(sB + 64,                  dB + 16384);
  STAGE2(sB + 128 * D_MODEL + 64,  dB + 16384 + 8192);
  STAGE2(sA + 64,                  dA + 16384);
  asm volatile("s_waitcnt vmcnt(6)" ::: "memory");
  __builtin_amdgcn_s_barrier();

  for (int i = 0; i < 7; ++i) {
    const int k1o = (2 * i + 1) * 64;
    const int k2o = (2 * i + 2) * 64;
    const int k3o = (2 * i + 3) * 64;
    PHASE(0, A0, B0, 1, STAGE2(sA + 128 * D_MODEL + k1o, dA + 16384 + 8192), -1);
    PHASE(1, A0, B0, 0, STAGE2(sB + k2o, dB), -1);
    PHASE(2, A0, B0, 0, STAGE2(sB + 128 * D_MODEL + k2o, dB + 8192), -1);
    PHASE(3, A0, B0, 0, STAGE2(sA + k2o, dA), 6);
    PHASE(0, A1, B1, 1, STAGE2(sA + 128 * D_MODEL + k2o, dA + 8192), -1);
    PHASE(1, A1, B1, 0, STAGE2(sB + k3o, dB + 16384), -1);
    PHASE(2, A1, B1, 0, STAGE2(sB + 128 * D_MODEL + k3o, dB + 16384 + 8192), -1);
    PHASE(3, A1, B1, 0, STAGE2(sA + k3o, dA + 16384), 6);
  }
  // epilogue iteration: ktiles 14 (buf0) and 15 (buf1)
  PHASE(0, A0, B0, 1, STAGE2(sA + 128 * D_MODEL + 15 * 64, dA + 16384 + 8192), -1);
  PHASE(1, A0, B0, 0, NOSTAGE, -1);
  PHASE(2, A0, B0, 0, NOSTAGE, -1);
  PHASE(3, A0, B0, 0, NOSTAGE, 0);
  PHASE(0, A1, B1, 1, NOSTAGE, -1);
  PHASE(1, A1, B1, 0, NOSTAGE, -1);
  PHASE(2, A1, B1, 0, NOSTAGE, -1);
  PHASE(3, A1, B1, 0, NOSTAGE, -1);

  // bias vectors (after pipeline so vmcnt counts stay clean)
  if (t < 256) {
    tsi[t] = tb[b * SEQ + i0 + t];
    tsa[t] = aa[b * SEQ + i0 + t];
  } else {
    tsj[t - 256] = tb[b * SEQ + j0 + t - 256];
    tsb2[t - 256] = bb[b * SEQ + j0 + t - 256];
  }
  __syncthreads();

  float tj[4], bj[4];
  #pragma unroll
  for (int nt = 0; nt < 4; nt++) {
    tj[nt] = tsj[wn * 64 + nt * 16 + l16];
    bj[nt] = tsb2[wn * 64 + nt * 16 + l16];
  }
  #pragma unroll
  for (int m8 = 0; m8 < 8; m8++) {
    #pragma unroll
    for (int rr = 0; rr < 4; rr++) {
      const int il = wm * 128 + (m8 >> 1) * 32 + (m8 & 1) * 16 + quad * 4 + rr;
      const float ti = tsi[il];
      const float ai = tsa[il];
      float* cp =
          out + ((size_t)(b * SEQ + i0 + il)) * SEQ + j0 + wn * 64 + l16;
      #pragma unroll
      for (int nt = 0; nt < 4; nt++) {
        const float num = tj[nt] - ti;
        const float den = fmaf(-tj[nt], ti, 1.0f);
        const float obias = 5.0f * num * __builtin_amdgcn_rcpf(den);
        cp[nt * 16] = SCALE * acc[m8][nt][rr] + ai + bj[nt] + obias;
      }
    }
  }
}

extern "C" void kernel_launch(void* const* d_in, const int* in_sizes, int n_in,
                              void* d_out, int out_size, void* d_ws,
                              size_t ws_size, hipStream_t stream) {
  const float* x  = (const float*)d_in[0];
  const float* Wq = (const float*)d_in[1];
  const float* bq = (const float*)d_in[2];
  const float* Wk = (const float*)d_in[3];
  const float* bk = (const float*)d_in[4];
  const float* Wo = (const float*)d_in[5];
  const float* bo = (const float*)d_in[6];
  float* out = (float*)d_out;

  char* ws = (char*)d_ws;
  unsigned short* xb  = (unsigned short*)(ws);                      // 16 MiB
  unsigned short* Zb  = (unsigned short*)(ws + (16ull << 20));      // 16 MiB
  unsigned short* Wqb = (unsigned short*)(ws + (32ull << 20));      // 2 MiB
  unsigned short* Wkb = (unsigned short*)(ws + (34ull << 20));      // 2 MiB
  unsigned short* Mt  = (unsigned short*)(ws + (36ull << 20));      // 2 MiB
  float* tb = (float*)(ws + (38ull << 20));                         // 32 KiB
  float* aa = (float*)(ws + (38ull << 20) + (32ull << 10));         // 32 KiB
  float* bb = (float*)(ws + (38ull << 20) + (64ull << 10));         // 32 KiB
  float* u  = (float*)(ws + (38ull << 20) + (96ull << 10));         // 4 KiB
  float* v  = (float*)(ws + (38ull << 20) + (100ull << 10));        // 4 KiB
  float* sc = (float*)(ws + (38ull << 20) + (104ull << 10));        // 4 B

  wcvt_kernel<<<2049, 256, 0, stream>>>(Wq, Wk, bq, bk, Wqb, Wkb, u, v, sc);
  prep_x_kernel<<<8192, 256, 0, stream>>>(x, Wo, bo, u, v, sc, xb, tb, aa, bb);
  wmm_kernel<<<dim3(8, 8), 256, 0, stream>>>(Wkb, Wqb, Mt);
  zgen_kernel<<<dim3(64, 8), 256, 0, stream>>>(xb, Mt, Zb);
  zxt_kernel<<<dim3(8, 8, 4), 512, 0, stream>>>(Zb, xb, tb, aa, bb, out);
}

// Round 4
// 182.693 us; speedup vs baseline: 1.0877x; 1.0624x over previous
//
#include <hip/hip_runtime.h>
#include <math.h>

#define D_MODEL 1024
#define SEQ 2048
#define SCALE 0.03125f

using bf16x8 = __attribute__((ext_vector_type(8))) short;
using f32x4  = __attribute__((ext_vector_type(4))) float;

__device__ __forceinline__ unsigned short f2bf(float f) {
  union { float f; unsigned int u; } v; v.f = f;
  return (unsigned short)((v.u + 0x7fffu + ((v.u >> 16) & 1u)) >> 16);
}

__device__ __forceinline__ void async_cp16(const void* g, void* l) {
  __builtin_amdgcn_global_load_lds(
      (const __attribute__((address_space(1))) void*)g,
      (__attribute__((address_space(3))) void*)l, 16, 0, 0);
}

// ============================================================================
// v4 core: 128x128 tile, 256 threads (4 waves, 2M x 2N, per-wave 64x64),
// BK=64, double-buffered LDS = 2 x (128x64 A + 128x64 B) bf16 = 64 KiB
// -> 2 blocks/CU co-resident (the round-0 overlap mechanism) with BK64's
// 32-MFMA-per-barrier density (2x round-0). LDS swizzle: 16B chunk c of
// row r stored at physical chunk c^(r&7) (2-way bank alias = free;
// verified 0 conflicts in rounds 2/3). Staging pre-swizzles the GLOBAL
// source (global_load_lds writes linearly). One __syncthreads per K-tile
// (full drain, round-0-proven; masked by the co-resident block).
// ============================================================================

// per-thread pre-swizzled staging pointer: thread t covers rows
// r = (t>>3) + 32*round, physical chunk t&7 <- logical chunk (t&7)^(r&7)
// (32*round keeps r&7 invariant across rounds).
__device__ __forceinline__ const unsigned short* sptr(
    const unsigned short* base, int row0, int t) {
  const int rr = t >> 3;
  const int ck = (t & 7) ^ (rr & 7);
  return base + (size_t)(row0 + rr) * D_MODEL + ck * 8;
}

#define STG8(KT, BUF) {                                                    \
    const unsigned short* a_ = sA + (KT) * 64;                             \
    const unsigned short* b_ = sB + (KT) * 64;                             \
    unsigned short* da_ = As + (BUF) * 8192 + t * 8;                       \
    unsigned short* db_ = Bs + (BUF) * 8192 + t * 8;                       \
    async_cp16(a_,                 da_);                                   \
    async_cp16(a_ + 32 * D_MODEL,  da_ + 2048);                            \
    async_cp16(a_ + 64 * D_MODEL,  da_ + 4096);                            \
    async_cp16(a_ + 96 * D_MODEL,  da_ + 6144);                            \
    async_cp16(b_,                 db_);                                   \
    async_cp16(b_ + 32 * D_MODEL,  db_ + 2048);                            \
    async_cp16(b_ + 64 * D_MODEL,  db_ + 4096);                            \
    async_cp16(b_ + 96 * D_MODEL,  db_ + 6144);                            \
  }

__device__ __forceinline__ void gemm128_bk64(
    const unsigned short* sA, const unsigned short* sB,
    unsigned short* As, unsigned short* Bs, int t, f32x4 acc[4][4]) {
  const int lane = t & 63, w = t >> 6;
  const int wm = w >> 1, wn = w & 1;
  const int l16 = lane & 15, quad = lane >> 4, x7 = l16 & 7;
  const int c0 = (quad ^ x7) * 8, c1 = ((4 | quad) ^ x7) * 8;

  STG8(0, 0);
  __syncthreads();

  #pragma unroll 2
  for (int kk = 0; kk < 16; ++kk) {
    const int cur = (kk & 1) * 8192;
    if (kk < 15) STG8(kk + 1, (kk & 1) ^ 1);
    bf16x8 afr[4][2], bfr[4][2];
    #pragma unroll
    for (int mt = 0; mt < 4; mt++) {
      const int base = cur + (wm * 64 + mt * 16 + l16) * 64;
      afr[mt][0] = *(const bf16x8*)(As + base + c0);
      afr[mt][1] = *(const bf16x8*)(As + base + c1);
    }
    #pragma unroll
    for (int nt = 0; nt < 4; nt++) {
      const int base = cur + (wn * 64 + nt * 16 + l16) * 64;
      bfr[nt][0] = *(const bf16x8*)(Bs + base + c0);
      bfr[nt][1] = *(const bf16x8*)(Bs + base + c1);
    }
    #pragma unroll
    for (int ks = 0; ks < 2; ks++)
      #pragma unroll
      for (int mt = 0; mt < 4; mt++)
        #pragma unroll
        for (int nt = 0; nt < 4; nt++)
          acc[mt][nt] = __builtin_amdgcn_mfma_f32_16x16x32_bf16(
              afr[mt][ks], bfr[nt][ks], acc[mt][nt], 0, 0, 0);
    __syncthreads();
  }
}

__device__ __forceinline__ void store_c_bf16(f32x4 acc[4][4],
                                             unsigned short* C, int ldc,
                                             int m0, int n0, int tid) {
  const int lane = tid & 63, w = tid >> 6;
  const int wm = w >> 1, wn = w & 1;
  const int l16 = lane & 15, quad = lane >> 4;
  #pragma unroll
  for (int mt = 0; mt < 4; mt++) {
    #pragma unroll
    for (int r = 0; r < 4; r++) {
      const int row = m0 + wm * 64 + mt * 16 + quad * 4 + r;
      unsigned short* cp = C + (size_t)row * ldc + n0 + wn * 64 + l16;
      #pragma unroll
      for (int nt = 0; nt < 4; nt++) cp[nt * 16] = f2bf(acc[mt][nt][r]);
    }
  }
}

// ---- wcvt: W fp32 -> bf16 rows; u = Wq bk, v = Wk bq, sc = scale*(bq.bk) ----
__global__ __launch_bounds__(256) void wcvt_kernel(
    const float* __restrict__ Wq, const float* __restrict__ Wk,
    const float* __restrict__ bq, const float* __restrict__ bk,
    unsigned short* __restrict__ Wqb, unsigned short* __restrict__ Wkb,
    float* __restrict__ u, float* __restrict__ v, float* __restrict__ sc) {
  const int blk = blockIdx.x, tid = threadIdx.x;
  __shared__ float red[4];
  float p;
  if (blk < 2048) {
    const bool isq = blk < 1024;
    const int row = blk & 1023;
    const float* W = isq ? Wq : Wk;
    const float* bias = isq ? bk : bq;
    const float4 wv = ((const float4*)(W + (size_t)row * D_MODEL))[tid];
    const float4 bv = ((const float4*)bias)[tid];
    ushort4 o;
    o.x = f2bf(wv.x); o.y = f2bf(wv.y); o.z = f2bf(wv.z); o.w = f2bf(wv.w);
    ((ushort4*)((isq ? Wqb : Wkb) + (size_t)row * D_MODEL))[tid] = o;
    p = wv.x * bv.x + wv.y * bv.y + wv.z * bv.z + wv.w * bv.w;
    #pragma unroll
    for (int off = 32; off > 0; off >>= 1) p += __shfl_down(p, off, 64);
    if ((tid & 63) == 0) red[tid >> 6] = p;
    __syncthreads();
    if (tid == 0) (isq ? u : v)[row] = red[0] + red[1] + red[2] + red[3];
  } else {
    const float4 a = ((const float4*)bq)[tid];
    const float4 b = ((const float4*)bk)[tid];
    p = a.x * b.x + a.y * b.y + a.z * b.z + a.w * b.w;
    #pragma unroll
    for (int off = 32; off > 0; off >>= 1) p += __shfl_down(p, off, 64);
    if ((tid & 63) == 0) red[tid >> 6] = p;
    __syncthreads();
    if (tid == 0) sc[0] = SCALE * (red[0] + red[1] + red[2] + red[3]);
  }
}

// ---- prep_x: xb=bf16(x); t=tanh(x.Wo+bo); aa=scale*(x.u)+sc; bb=scale*(x.v) ----
__global__ __launch_bounds__(256) void prep_x_kernel(
    const float* __restrict__ x, const float* __restrict__ Wo,
    const float* __restrict__ bo, const float* __restrict__ u,
    const float* __restrict__ v, const float* __restrict__ sc,
    unsigned short* __restrict__ xb, float* __restrict__ tb,
    float* __restrict__ aa, float* __restrict__ bb) {
  const int m = blockIdx.x, tid = threadIdx.x;
  const float4 xv = ((const float4*)(x + (size_t)m * D_MODEL))[tid];
  const float4 wv = ((const float4*)Wo)[tid];
  const float4 uv = ((const float4*)u)[tid];
  const float4 vv = ((const float4*)v)[tid];
  ushort4 o;
  o.x = f2bf(xv.x); o.y = f2bf(xv.y); o.z = f2bf(xv.z); o.w = f2bf(xv.w);
  ((ushort4*)(xb + (size_t)m * D_MODEL))[tid] = o;
  float p0 = xv.x * wv.x + xv.y * wv.y + xv.z * wv.z + xv.w * wv.w;
  float p1 = xv.x * uv.x + xv.y * uv.y + xv.z * uv.z + xv.w * uv.w;
  float p2 = xv.x * vv.x + xv.y * vv.y + xv.z * vv.z + xv.w * vv.w;
  #pragma unroll
  for (int off = 32; off > 0; off >>= 1) {
    p0 += __shfl_down(p0, off, 64);
    p1 += __shfl_down(p1, off, 64);
    p2 += __shfl_down(p2, off, 64);
  }
  __shared__ float red[3][4];
  if ((tid & 63) == 0) {
    red[0][tid >> 6] = p0; red[1][tid >> 6] = p1; red[2][tid >> 6] = p2;
  }
  __syncthreads();
  if (tid == 0) {
    tb[m] = tanhf(red[0][0] + red[0][1] + red[0][2] + red[0][3] + bo[0]);
    aa[m] = SCALE * (red[1][0] + red[1][1] + red[1][2] + red[1][3]) + sc[0];
    bb[m] = SCALE * (red[2][0] + red[2][1] + red[2][2] + red[2][3]);
  }
}

// ---- wmm: Mt[d2,d1] = sum_e Wk[d2,e]*Wq[d1,e]  (A=Wkb, B^T=Wqb) ----
__global__ __launch_bounds__(256, 2) void wmm_kernel(
    const unsigned short* __restrict__ Wkb,
    const unsigned short* __restrict__ Wqb, unsigned short* __restrict__ Mt) {
  const int m0 = blockIdx.x * 128, n0 = blockIdx.y * 128;
  __shared__ unsigned short As[2 * 8192], Bs[2 * 8192];
  const int t = threadIdx.x;
  f32x4 acc[4][4];
  #pragma unroll
  for (int i = 0; i < 4; i++)
    #pragma unroll
    for (int j = 0; j < 4; j++) acc[i][j] = f32x4{0.f, 0.f, 0.f, 0.f};
  gemm128_bk64(sptr(Wkb, m0, t), sptr(Wqb, n0, t), As, Bs, t, acc);
  store_c_bf16(acc, Mt, D_MODEL, m0, n0, t);
}

// ---- zgen: Zb = xb @ M  (B^T = Mt rows) ----
__global__ __launch_bounds__(256, 2) void zgen_kernel(
    const unsigned short* __restrict__ xb,
    const unsigned short* __restrict__ Mt, unsigned short* __restrict__ Zb) {
  const int m0 = blockIdx.x * 128, n0 = blockIdx.y * 128;
  __shared__ unsigned short As[2 * 8192], Bs[2 * 8192];
  const int t = threadIdx.x;
  f32x4 acc[4][4];
  #pragma unroll
  for (int i = 0; i < 4; i++)
    #pragma unroll
    for (int j = 0; j < 4; j++) acc[i][j] = f32x4{0.f, 0.f, 0.f, 0.f};
  gemm128_bk64(sptr(xb, m0, t), sptr(Mt, n0, t), As, Bs, t, acc);
  store_c_bf16(acc, Zb, D_MODEL, m0, n0, t);
}

// ---- zxt: out[b,i,j] = scale*(Z_i . x_j) + aa_i + bb_j + 5*tanh(s_j-s_i) ----
// v4 core + T1 XCD rectangle map: 1024 blocks = 128/XCD; each XCD owns a
// 4(i) x 8(j) rectangle of 128^2 tiles per batch -> L2 working set
// 4 A-panels + 8 B-panels = 3 MiB <= 4 MiB per-XCD L2. Bijective:
// n = z*256+y*16+x; xcd=n&7; q=n>>3; b=q>>5; r=q&31;
// i_t=(xcd>>1)*4+(r>>3); j_t=(xcd&1)*8+(r&7).
__global__ __launch_bounds__(256, 2) void zxt_kernel(
    const unsigned short* __restrict__ Zb, const unsigned short* __restrict__ xb,
    const float* __restrict__ tb, const float* __restrict__ aa,
    const float* __restrict__ bb, float* __restrict__ out) {
  __shared__ unsigned short As[2 * 8192], Bs[2 * 8192];
  __shared__ float tsi[128], tsa[128], tsj[128], tsb2[128];
  const int n = blockIdx.z * 256 + blockIdx.y * 16 + blockIdx.x;
  const int xcd = n & 7, q = n >> 3;
  const int b = q >> 5, r = q & 31;
  const int i0 = ((xcd >> 1) * 4 + (r >> 3)) * 128;
  const int j0 = ((xcd & 1) * 8 + (r & 7)) * 128;
  const int t = threadIdx.x;

  // bias vectors up front (v4 core's __syncthreads drains cover them)
  if (t < 128) {
    tsi[t] = tb[b * SEQ + i0 + t];
    tsa[t] = aa[b * SEQ + i0 + t];
  } else {
    tsj[t - 128] = tb[b * SEQ + j0 + t - 128];
    tsb2[t - 128] = bb[b * SEQ + j0 + t - 128];
  }

  f32x4 acc[4][4];
  #pragma unroll
  for (int i = 0; i < 4; i++)
    #pragma unroll
    for (int j = 0; j < 4; j++) acc[i][j] = f32x4{0.f, 0.f, 0.f, 0.f};
  gemm128_bk64(sptr(Zb + (size_t)b * SEQ * D_MODEL, i0, t),
               sptr(xb + (size_t)b * SEQ * D_MODEL, j0, t), As, Bs, t, acc);

  const int lane = t & 63, w = t >> 6;
  const int wm = w >> 1, wn = w & 1;
  const int l16 = lane & 15, quad = lane >> 4;
  float tj[4], bj[4];
  #pragma unroll
  for (int nt = 0; nt < 4; nt++) {
    tj[nt] = tsj[wn * 64 + nt * 16 + l16];
    bj[nt] = tsb2[wn * 64 + nt * 16 + l16];
  }
  #pragma unroll
  for (int mt = 0; mt < 4; mt++) {
    #pragma unroll
    for (int rr = 0; rr < 4; rr++) {
      const int il = wm * 64 + mt * 16 + quad * 4 + rr;
      const float ti = tsi[il];
      const float ai = tsa[il];
      float* cp =
          out + ((size_t)(b * SEQ + i0 + il)) * SEQ + j0 + wn * 64 + l16;
      #pragma unroll
      for (int nt = 0; nt < 4; nt++) {
        const float num = tj[nt] - ti;
        const float den = fmaf(-tj[nt], ti, 1.0f);
        const float obias = 5.0f * num * __builtin_amdgcn_rcpf(den);
        cp[nt * 16] = SCALE * acc[mt][nt][rr] + ai + bj[nt] + obias;
      }
    }
  }
}

extern "C" void kernel_launch(void* const* d_in, const int* in_sizes, int n_in,
                              void* d_out, int out_size, void* d_ws,
                              size_t ws_size, hipStream_t stream) {
  const float* x  = (const float*)d_in[0];
  const float* Wq = (const float*)d_in[1];
  const float* bq = (const float*)d_in[2];
  const float* Wk = (const float*)d_in[3];
  const float* bk = (const float*)d_in[4];
  const float* Wo = (const float*)d_in[5];
  const float* bo = (const float*)d_in[6];
  float* out = (float*)d_out;

  char* ws = (char*)d_ws;
  unsigned short* xb  = (unsigned short*)(ws);                      // 16 MiB
  unsigned short* Zb  = (unsigned short*)(ws + (16ull << 20));      // 16 MiB
  unsigned short* Wqb = (unsigned short*)(ws + (32ull << 20));      // 2 MiB
  unsigned short* Wkb = (unsigned short*)(ws + (34ull << 20));      // 2 MiB
  unsigned short* Mt  = (unsigned short*)(ws + (36ull << 20));      // 2 MiB
  float* tb = (float*)(ws + (38ull << 20));                         // 32 KiB
  float* aa = (float*)(ws + (38ull << 20) + (32ull << 10));         // 32 KiB
  float* bb = (float*)(ws + (38ull << 20) + (64ull << 10));         // 32 KiB
  float* u  = (float*)(ws + (38ull << 20) + (96ull << 10));         // 4 KiB
  float* v  = (float*)(ws + (38ull << 20) + (100ull << 10));        // 4 KiB
  float* sc = (float*)(ws + (38ull << 20) + (104ull << 10));        // 4 B

  wcvt_kernel<<<2049, 256, 0, stream>>>(Wq, Wk, bq, bk, Wqb, Wkb, u, v, sc);
  prep_x_kernel<<<8192, 256, 0, stream>>>(x, Wo, bo, u, v, sc, xb, tb, aa, bb);
  wmm_kernel<<<dim3(8, 8), 256, 0, stream>>>(Wkb, Wqb, Mt);
  zgen_kernel<<<dim3(64, 8), 256, 0, stream>>>(xb, Mt, Zb);
  zxt_kernel<<<dim3(16, 16, 4), 256, 0, stream>>>(Zb, xb, tb, aa, bb, out);
}